// Round 7
// baseline (201.943 us; speedup 1.0000x reference)
//
#include <hip/hip_runtime.h>

#define HID 768
#define NTHREADS 256
#define WPB 4    // waves per block

// ws layout: [0..3] int count; [64..] int2 entries[T*D]
#define ENTRIES_OFF 64

// ---- kernel 1: compact valid steps into a dense t-major list ---------------
// One thread per (t,d) slot, idx = t*D + d (t-major so the compacted list is
// token-clustered -> h-row L1 reuse among adjacent gather waves, W rows
// scattered -> no same-address L2 contention, which R6 proved catastrophic).
// entry = (t, node<<1|bit). ~27k of 41k slots are valid.
__global__ __launch_bounds__(NTHREADS) void huffman_pack_kernel(
    const int*  __restrict__ target,      // [T]
    const int*  __restrict__ path_nodes,  // [V, D]
    const int*  __restrict__ path_bits,   // [V, D]
    const void* __restrict__ path_mask,   // [V, D] bool (byte OR int32 layout)
    int*        __restrict__ count,       // [1], pre-zeroed
    int2*       __restrict__ entries,     // [T*D]
    int T, int D)
{
    const int idx = blockIdx.x * NTHREADS + threadIdx.x;   // idx = t*D + d
    if (idx >= T * D) return;
    const int t = idx / D;
    const int d = idx - t * D;

    // Mask layout detect: mask[0,0..3] all true (min Huffman depth >> 4),
    // byte layout reads 0x01010101, int32 layout reads 1.
    const bool mask_is_byte = (*(const unsigned int*)path_mask) > 1u;

    const int  v  = target[t];
    const long pr = (long)v * D + d;
    const bool valid = mask_is_byte
        ? (((const unsigned char*)path_mask)[pr] != 0)
        : (((const int*)path_mask)[pr] != 0);

    if (valid) {
        const int n = path_nodes[pr];
        const int b = path_bits[pr];
        const int pos = atomicAdd(count, 1);   // wave-coalesced by compiler
        entries[pos] = make_int2(t, (n << 1) | b);
    }
}

// ---- kernel 2: one wave per compacted step ---------------------------------
// Per wave: 1 x 8 B entry load -> 6 coalesced float4 W-loads + 6 float2
// h-loads (all 12 independent, ~36 VGPRs in flight -> no re-serialization)
// -> 24 FMAs on the DIFFERENCE accumulator (softmax needs only l0-l1)
// -> 6-level butterfly (half of R2's 12) -> sigmoid-form CE -> block
// combine -> at most one atomicAdd per block.
__global__ __launch_bounds__(NTHREADS) void huffman_gather_kernel(
    const float* __restrict__ hidden,     // [T, H]
    const float* __restrict__ node_W,     // [V-1, H, 2]
    const float* __restrict__ node_b,     // [V-1, 2]
    const int*   __restrict__ count,      // [1] valid-step count
    const int2*  __restrict__ entries,    // [count]
    float*       __restrict__ out)        // [1], pre-zeroed
{
    const int wave = threadIdx.x >> 6;
    const int lane = threadIdx.x & 63;
    const int slot = blockIdx.x * WPB + wave;

    float lsum = 0.0f;

    if (slot < *count) {
        const int2 e = entries[slot];
        const int  t = e.x;
        const int  n = e.y >> 1;

        const float4* __restrict__ w4 =
            (const float4*)(node_W + (long)n * (HID * 2));
        const float2* __restrict__ h2 =
            (const float2*)(hidden + (long)t * HID);
        const float2 bb = *(const float2*)(node_b + 2 * n);

        float accd = 0.0f;
        #pragma unroll
        for (int j = 0; j < HID / 2 / 64; ++j) {   // 6 indep W + 6 indep h loads
            const int q  = j * 64 + lane;          // k-pair: k = 2q, 2q+1
            const float4 w = w4[q];                // W[n,2q,{0,1}], W[n,2q+1,{0,1}]
            const float2 h = h2[q];
            accd += h.x * (w.x - w.y) + h.y * (w.z - w.w);
        }

        #pragma unroll
        for (int off = 32; off > 0; off >>= 1)
            accd += __shfl_xor(accd, off, 64);

        // delta-form double-softmax CE (verified exact since R5):
        // p0 = sigmoid(delta), p1 = 1-p0, ce = log(e^p0+e^p1) - p_bit.
        const float delta = accd + (bb.x - bb.y);
        const float p0  = 1.0f / (1.0f + __expf(-delta));
        const float p1  = 1.0f - p0;
        const float lse = __logf(__expf(p0) + __expf(p1));
        const float pb  = (e.y & 1) ? p1 : p0;
        lsum = lse - pb;                   // identical in all lanes
    }

    __shared__ float wsum[WPB];
    if (lane == 0) wsum[wave] = lsum;
    __syncthreads();
    if (threadIdx.x == 0) {
        const float tot = (wsum[0] + wsum[1]) + (wsum[2] + wsum[3]);
        if (tot != 0.0f) atomicAdd(out, tot);
    }
}

extern "C" void kernel_launch(void* const* d_in, const int* in_sizes, int n_in,
                              void* d_out, int out_size, void* d_ws, size_t ws_size,
                              hipStream_t stream) {
    const float* hidden     = (const float*)d_in[0];
    const int*   target     = (const int*)d_in[1];
    const float* node_W     = (const float*)d_in[2];
    const float* node_b     = (const float*)d_in[3];
    const int*   path_nodes = (const int*)d_in[4];
    const int*   path_bits  = (const int*)d_in[5];
    const void*  path_mask  = (const void*)d_in[6];
    float* out = (float*)d_out;

    const int T   = in_sizes[0] / HID;        // B*S = 2048
    const int Vm1 = in_sizes[3] / 2;          // V-1 = 9999
    const int V   = Vm1 + 1;
    const int D   = in_sizes[4] / V;          // padded path depth (~20)
    const int nslots = T * D;

    int*  count   = (int*)d_ws;
    int2* entries = (int2*)((char*)d_ws + ENTRIES_OFF);

    // d_out and d_ws are re-poisoned (0xAA) before every timed call.
    hipMemsetAsync(d_out, 0, sizeof(float), stream);
    hipMemsetAsync(count, 0, sizeof(int), stream);

    const int pblocks = (nslots + NTHREADS - 1) / NTHREADS;
    huffman_pack_kernel<<<dim3(pblocks), dim3(NTHREADS), 0, stream>>>(
        target, path_nodes, path_bits, path_mask, count, entries, T, D);

    const int gblocks = (nslots + WPB - 1) / WPB;   // waves beyond count exit fast
    huffman_gather_kernel<<<dim3(gblocks), dim3(NTHREADS), 0, stream>>>(
        hidden, node_W, node_b, count, entries, out);
}